// Round 3
// baseline (934.885 us; speedup 1.0000x reference)
//
#include <hip/hip_runtime.h>
#include <math.h>

// ---------------- Problem constants ----------------
#define B_SZ 4
#define L_SEQ 1024
#define D_MODEL 1024
#define D_INNER 2048
#define D_STATE 16
#define N_BC 2080
#define M_ROWS (B_SZ * L_SEQ)   // 4096

typedef unsigned short u16;
typedef __bf16 bf16x8 __attribute__((ext_vector_type(8)));
typedef float f32x4 __attribute__((ext_vector_type(4)));

__device__ __forceinline__ float bf2f(u16 u) {
    union { unsigned int i; float f; } v; v.i = ((unsigned int)u) << 16; return v.f;
}
__device__ __forceinline__ u16 f2bf(float f) {
    union { float f; unsigned int i; } v; v.f = f;
    return (u16)((v.i + 0x7FFFu + ((v.i >> 16) & 1u)) >> 16);   // RNE
}
__device__ __forceinline__ float softplus_f(float v) {
    return fmaxf(v, 0.f) + log1pf(expf(-fabsf(v)));
}
__device__ __forceinline__ float silu_f(float v) {
    return v / (1.f + expf(-v));
}

// ---------------- f32 -> bf16 convert ----------------
__global__ __launch_bounds__(256) void cvt_bf16_k(const float* __restrict__ in,
                                                  u16* __restrict__ out, int n4) {
    int i = blockIdx.x * 256 + threadIdx.x;
    if (i >= n4) return;
    float4 v = *(const float4*)(in + (size_t)i * 4);
    ushort4 o;
    o.x = f2bf(v.x); o.y = f2bf(v.y); o.z = f2bf(v.z); o.w = f2bf(v.w);
    *(ushort4*)(out + (size_t)i * 4) = o;
}

// ---------------- bf16 MFMA GEMM: C[M,N] = A[M,K] * W[N,K]^T ----------------
// 128x128 tile, BK=32, 4 waves, each wave 64x64 (4x4 fragments 16x16x32).
// EPI: 0 f32 store; 1 softplus(v+bias[n]) f32; 2 bf16 store; 3 split dt/BC
template <int EPI>
__global__ __launch_bounds__(256, 2) void gemm_bf16(
    const u16* __restrict__ A, int lda,
    const u16* __restrict__ W, int ldw,
    int M, int N, int K, int ldc,
    const float* __restrict__ bias,
    float* __restrict__ Cf, u16* __restrict__ Cb, float* __restrict__ Caux)
{
    __shared__ uint4 As[512];   // [128 rows][4 quads of 8 bf16], quad XOR-swizzled
    __shared__ uint4 Ws[512];

    const int tid = threadIdx.x;
    const int lane = tid & 63;
    const int wave = tid >> 6;
    const int wr = wave >> 1;           // 0..1 row of 64
    const int wc = wave & 1;            // 0..1 col of 64
    const int bm = blockIdx.y * 128;
    const int bn = blockIdx.x * 128;
    const int l15 = lane & 15;
    const int lq = lane >> 4;           // k-quarter 0..3

    f32x4 acc[4][4];
#pragma unroll
    for (int m = 0; m < 4; ++m)
#pragma unroll
        for (int n = 0; n < 4; ++n) acc[m][n] = f32x4{0.f, 0.f, 0.f, 0.f};

    for (int k0 = 0; k0 < K; k0 += 32) {
        // stage 128x32 bf16 tiles of A and W (reg-staged, swizzled quad)
#pragma unroll
        for (int h = 0; h < 2; ++h) {
            int e = tid + h * 256;      // 0..511, 16B chunk index
            int row = e >> 2;
            int q = e & 3;
            int sidx = row * 4 + (q ^ (row & 3));
            As[sidx] = *(const uint4*)(A + (size_t)(bm + row) * lda + k0 + q * 8);
            int wrow = bn + row; if (wrow >= N) wrow = N - 1;
            Ws[sidx] = *(const uint4*)(W + (size_t)wrow * ldw + k0 + q * 8);
        }
        __syncthreads();

        bf16x8 af[4], bf[4];
#pragma unroll
        for (int m = 0; m < 4; ++m) {
            int r = wr * 64 + m * 16 + l15;
            af[m] = *reinterpret_cast<const bf16x8*>(&As[r * 4 + (lq ^ (r & 3))]);
        }
#pragma unroll
        for (int n = 0; n < 4; ++n) {
            int r = wc * 64 + n * 16 + l15;
            bf[n] = *reinterpret_cast<const bf16x8*>(&Ws[r * 4 + (lq ^ (r & 3))]);
        }
#pragma unroll
        for (int m = 0; m < 4; ++m)
#pragma unroll
            for (int n = 0; n < 4; ++n)
                acc[m][n] = __builtin_amdgcn_mfma_f32_16x16x32_bf16(af[m], bf[n], acc[m][n], 0, 0, 0);
        __syncthreads();
    }

    // epilogue: D layout col=lane&15, row=(lane>>4)*4+reg  [m89-verified]
#pragma unroll
    for (int m = 0; m < 4; ++m) {
#pragma unroll
        for (int n = 0; n < 4; ++n) {
#pragma unroll
            for (int j = 0; j < 4; ++j) {
                int gr = bm + wr * 64 + m * 16 + lq * 4 + j;
                int gc = bn + wc * 64 + n * 16 + l15;
                float v = acc[m][n][j];
                if (EPI == 0) {
                    if (gc < N) Cf[(size_t)gr * ldc + gc] = v;
                } else if (EPI == 1) {
                    if (gc < N) Cf[(size_t)gr * ldc + gc] = softplus_f(v + bias[gc]);
                } else if (EPI == 2) {
                    if (gc < N) Cb[(size_t)gr * ldc + gc] = f2bf(v);
                } else { // 3: cols<2048 -> dt_bf (bf16, ld 2048); 2048..2079 -> BC f32 (ld 32)
                    if (gc < D_INNER) Cb[(size_t)gr * D_INNER + gc] = f2bf(v);
                    else if (gc < N_BC) Caux[(size_t)gr * 32 + (gc - D_INNER)] = v;
                }
            }
        }
    }
}

// ---------------- depthwise causal conv (K=4) + SiLU, bf16 in/out ----------
__global__ __launch_bounds__(256) void conv_silu_k(
    const u16* __restrict__ xz,     // [4096][4096] bf16, xi = cols 0..2047
    const float* __restrict__ cw,   // [2048][4] f32
    const float* __restrict__ cb,   // [2048]
    u16* __restrict__ xc)           // [4096][2048] bf16
{
    int idx = blockIdx.x * 256 + threadIdx.x;
    if (idx >= M_ROWS * D_INNER) return;
    int d = idx & (D_INNER - 1);
    int m = idx >> 11;
    int l = m & (L_SEQ - 1);
    float4 w = *(const float4*)(cw + d * 4);
    const u16* base = xz + (size_t)m * (2 * D_INNER) + d;
    float acc = cb[d];
    acc = fmaf(bf2f(base[0]), w.w, acc);
    if (l >= 1) acc = fmaf(bf2f(base[-(2 * D_INNER)]), w.z, acc);
    if (l >= 2) acc = fmaf(bf2f(base[-2 * (2 * D_INNER)]), w.y, acc);
    if (l >= 3) acc = fmaf(bf2f(base[-3 * (2 * D_INNER)]), w.x, acc);
    xc[idx] = f2bf(silu_f(acc));
}

// ---------------- selective scan + x*D + silu(z) gating --------------------
// block 256 = 16 d x 16 n; grid = B * D_INNER/16 = 512
__global__ __launch_bounds__(256) void scan_k(
    const float* __restrict__ delta,   // [4096][2048] f32
    const u16* __restrict__ xc,        // [4096][2048] bf16
    const float* __restrict__ BC,      // [4096][32] f32: B=0..15, C=16..31
    const u16* __restrict__ xz,        // z at col 2048+d, ld 4096, bf16
    const float* __restrict__ A_log,   // [2048][16]
    const float* __restrict__ Dp,      // [2048]
    u16* __restrict__ yg)              // [4096][2048] bf16
{
    const int b = blockIdx.x >> 7;
    const int dblk = blockIdx.x & 127;
    const int tid = threadIdx.x;
    const int dl = tid >> 4;
    const int n = tid & 15;
    const int d = dblk * 16 + dl;

    const float Ac = -expf(A_log[d * 16 + n]);
    const float Dv = Dp[d];
    float h = 0.f;
    const size_t row0 = (size_t)b * L_SEQ;

    float dv = delta[row0 * D_INNER + d];
    float xv = bf2f(xc[row0 * D_INNER + d]);
    float Bv = BC[row0 * 32 + n];
    float Cv = BC[row0 * 32 + 16 + n];

    for (int l = 0; l < L_SEQ; ++l) {
        float dv_n = 0.f, xv_n = 0.f, Bv_n = 0.f, Cv_n = 0.f;
        if (l + 1 < L_SEQ) {
            size_t mn = row0 + l + 1;
            dv_n = delta[mn * D_INNER + d];
            xv_n = bf2f(xc[mn * D_INNER + d]);
            Bv_n = BC[mn * 32 + n];
            Cv_n = BC[mn * 32 + 16 + n];
        }
        float dA = expf(dv * Ac);
        h = fmaf(dA, h, dv * Bv * xv);
        float py = Cv * h;
        py += __shfl_xor(py, 1);
        py += __shfl_xor(py, 2);
        py += __shfl_xor(py, 4);
        py += __shfl_xor(py, 8);
        if (n == 0) {
            size_t mm = row0 + l;
            float zv = bf2f(xz[mm * (2 * D_INNER) + D_INNER + d]);
            float yt = fmaf(xv, Dv, py);
            yg[mm * D_INNER + d] = f2bf(yt * silu_f(zv));
        }
        dv = dv_n; xv = xv_n; Bv = Bv_n; Cv = Cv_n;
    }
}

// ---------------- host launch ----------------
extern "C" void kernel_launch(void* const* d_in, const int* in_sizes, int n_in,
                              void* d_out, int out_size, void* d_ws, size_t ws_size,
                              hipStream_t stream)
{
    const float* x          = (const float*)d_in[0];
    const float* in_proj_w  = (const float*)d_in[1];
    const float* conv_w     = (const float*)d_in[2];
    const float* conv_b     = (const float*)d_in[3];
    const float* x_proj_w   = (const float*)d_in[4];
    const float* dt_proj_w  = (const float*)d_in[5];
    const float* dt_proj_b  = (const float*)d_in[6];
    const float* A_log      = (const float*)d_in[7];
    const float* D_param    = (const float*)d_in[8];
    const float* out_proj_w = (const float*)d_in[9];
    float* out = (float*)d_out;

    char* p = (char*)d_ws;
    u16* x_bf  = (u16*)p;  p += (size_t)M_ROWS * D_MODEL * 2;          // 8 MB
    u16* w1_bf = (u16*)p;  p += (size_t)2 * D_INNER * D_MODEL * 2;     // 8 MB
    u16* w3_bf = (u16*)p;  p += (size_t)N_BC * D_INNER * 2;            // 8.5 MB
    u16* w4_bf = (u16*)p;  p += (size_t)D_INNER * D_INNER * 2;         // 8 MB
    u16* w6_bf = (u16*)p;  p += (size_t)D_MODEL * D_INNER * 2;         // 4 MB
    u16* xz_bf = (u16*)p;  p += (size_t)M_ROWS * 2 * D_INNER * 2;      // 32 MB
    u16* xc_bf = (u16*)p;  p += (size_t)M_ROWS * D_INNER * 2;          // 16 MB
    u16* dt_bf = (u16*)p;  p += (size_t)M_ROWS * D_INNER * 2;          // 16 MB
    float* BC  = (float*)p; p += (size_t)M_ROWS * 32 * 4;              // 0.5 MB
    float* delta = (float*)p; p += (size_t)M_ROWS * D_INNER * 4;       // 32 MB
    u16* yg_bf = (u16*)p;                                              // 16 MB

    dim3 blk(256);
    auto cvt = [&](const float* src, u16* dst, size_t n) {
        int n4 = (int)(n / 4);
        cvt_bf16_k<<<dim3((n4 + 255) / 256), blk, 0, stream>>>(src, dst, n4);
    };
    cvt(x,          x_bf,  (size_t)M_ROWS * D_MODEL);
    cvt(in_proj_w,  w1_bf, (size_t)2 * D_INNER * D_MODEL);
    cvt(x_proj_w,   w3_bf, (size_t)N_BC * D_INNER);
    cvt(dt_proj_w,  w4_bf, (size_t)D_INNER * D_INNER);
    cvt(out_proj_w, w6_bf, (size_t)D_MODEL * D_INNER);

    // 1) xz = x @ in_proj^T -> bf16   [4096,4096] K=1024
    gemm_bf16<2><<<dim3(32, 32), blk, 0, stream>>>(
        x_bf, D_MODEL, w1_bf, D_MODEL, M_ROWS, 2 * D_INNER, D_MODEL, 2 * D_INNER,
        nullptr, nullptr, xz_bf, nullptr);

    // 2) conv + silu -> xc_bf
    conv_silu_k<<<dim3((M_ROWS * D_INNER) / 256), blk, 0, stream>>>(
        xz_bf, conv_w, conv_b, xc_bf);

    // 3) deltaBC = xc @ x_proj^T -> dt_bf (cols<2048) + BC f32   [4096,2080] K=2048
    gemm_bf16<3><<<dim3(17, 32), blk, 0, stream>>>(
        xc_bf, D_INNER, w3_bf, D_INNER, M_ROWS, N_BC, D_INNER, 0,
        nullptr, nullptr, dt_bf, BC);

    // 4) delta = softplus(dt @ dt_proj^T + b) -> f32   [4096,2048] K=2048
    gemm_bf16<1><<<dim3(16, 32), blk, 0, stream>>>(
        dt_bf, D_INNER, w4_bf, D_INNER, M_ROWS, D_INNER, D_INNER, D_INNER,
        dt_proj_b, delta, nullptr, nullptr);

    // 5) selective scan + gating -> yg_bf
    scan_k<<<dim3(B_SZ * (D_INNER / 16)), blk, 0, stream>>>(
        delta, xc_bf, BC, xz_bf, A_log, D_param, yg_bf);

    // 6) out = yg @ out_proj^T -> f32   [4096,1024] K=2048
    gemm_bf16<0><<<dim3(8, 32), blk, 0, stream>>>(
        yg_bf, D_INNER, w6_bf, D_INNER, M_ROWS, D_MODEL, D_INNER, D_MODEL,
        nullptr, out, nullptr, nullptr);
}

// Round 4
// 362.118 us; speedup vs baseline: 2.5817x; 2.5817x over previous
//
#include <hip/hip_runtime.h>
#include <math.h>

// ---------------- Problem constants ----------------
#define B_SZ 4
#define L_SEQ 1024
#define D_MODEL 1024
#define D_INNER 2048
#define D_STATE 16
#define N_BC 2080
#define M_ROWS (B_SZ * L_SEQ)   // 4096
#define CHUNK 32
#define NCH (L_SEQ / CHUNK)     // 32

typedef unsigned short u16;
typedef __bf16 bf16x8 __attribute__((ext_vector_type(8)));
typedef float f32x4 __attribute__((ext_vector_type(4)));

__device__ __forceinline__ float bf2f(u16 u) {
    union { unsigned int i; float f; } v; v.i = ((unsigned int)u) << 16; return v.f;
}
__device__ __forceinline__ u16 f2bf(float f) {
    union { float f; unsigned int i; } v; v.f = f;
    return (u16)((v.i + 0x7FFFu + ((v.i >> 16) & 1u)) >> 16);   // RNE
}
__device__ __forceinline__ float softplus_f(float v) {
    return fmaxf(v, 0.f) + log1pf(expf(-fabsf(v)));
}
__device__ __forceinline__ float silu_f(float v) {
    return v / (1.f + expf(-v));
}

// ---------------- f32 -> bf16 convert ----------------
__global__ __launch_bounds__(256) void cvt_bf16_k(const float* __restrict__ in,
                                                  u16* __restrict__ out, int n4) {
    int i = blockIdx.x * 256 + threadIdx.x;
    if (i >= n4) return;
    float4 v = *(const float4*)(in + (size_t)i * 4);
    ushort4 o;
    o.x = f2bf(v.x); o.y = f2bf(v.y); o.z = f2bf(v.z); o.w = f2bf(v.w);
    *(ushort4*)(out + (size_t)i * 4) = o;
}

// ---------------- bf16 MFMA GEMM: C[M,N] = A[M,K] * W[N,K]^T ----------------
// 128x128 tile, BK=32, 4 waves, each wave 64x64 (4x4 fragments 16x16x32).
// EPI: 0 f32 store; 1 softplus(v+bias[n]) f32; 2 bf16 store; 3 split dt/BC
template <int EPI>
__global__ __launch_bounds__(256, 2) void gemm_bf16(
    const u16* __restrict__ A, int lda,
    const u16* __restrict__ W, int ldw,
    int M, int N, int K, int ldc,
    const float* __restrict__ bias,
    float* __restrict__ Cf, u16* __restrict__ Cb, float* __restrict__ Caux)
{
    __shared__ uint4 As[512];   // [128 rows][4 quads of 8 bf16], quad XOR-swizzled
    __shared__ uint4 Ws[512];

    const int tid = threadIdx.x;
    const int lane = tid & 63;
    const int wave = tid >> 6;
    const int wr = wave >> 1;           // 0..1 row of 64
    const int wc = wave & 1;            // 0..1 col of 64
    const int bm = blockIdx.y * 128;
    const int bn = blockIdx.x * 128;
    const int l15 = lane & 15;
    const int lq = lane >> 4;           // k-quarter 0..3

    f32x4 acc[4][4];
#pragma unroll
    for (int m = 0; m < 4; ++m)
#pragma unroll
        for (int n = 0; n < 4; ++n) acc[m][n] = f32x4{0.f, 0.f, 0.f, 0.f};

    for (int k0 = 0; k0 < K; k0 += 32) {
        // stage 128x32 bf16 tiles of A and W (reg-staged, swizzled quad)
#pragma unroll
        for (int h = 0; h < 2; ++h) {
            int e = tid + h * 256;      // 0..511, 16B chunk index
            int row = e >> 2;
            int q = e & 3;
            int sidx = row * 4 + (q ^ (row & 3));
            As[sidx] = *(const uint4*)(A + (size_t)(bm + row) * lda + k0 + q * 8);
            int wrow = bn + row; if (wrow >= N) wrow = N - 1;
            Ws[sidx] = *(const uint4*)(W + (size_t)wrow * ldw + k0 + q * 8);
        }
        __syncthreads();

        bf16x8 af[4], bf[4];
#pragma unroll
        for (int m = 0; m < 4; ++m) {
            int r = wr * 64 + m * 16 + l15;
            af[m] = *reinterpret_cast<const bf16x8*>(&As[r * 4 + (lq ^ (r & 3))]);
        }
#pragma unroll
        for (int n = 0; n < 4; ++n) {
            int r = wc * 64 + n * 16 + l15;
            bf[n] = *reinterpret_cast<const bf16x8*>(&Ws[r * 4 + (lq ^ (r & 3))]);
        }
#pragma unroll
        for (int m = 0; m < 4; ++m)
#pragma unroll
            for (int n = 0; n < 4; ++n)
                acc[m][n] = __builtin_amdgcn_mfma_f32_16x16x32_bf16(af[m], bf[n], acc[m][n], 0, 0, 0);
        __syncthreads();
    }

    // epilogue: D layout col=lane&15, row=(lane>>4)*4+reg  [m89-verified]
#pragma unroll
    for (int m = 0; m < 4; ++m) {
#pragma unroll
        for (int n = 0; n < 4; ++n) {
#pragma unroll
            for (int j = 0; j < 4; ++j) {
                int gr = bm + wr * 64 + m * 16 + lq * 4 + j;
                int gc = bn + wc * 64 + n * 16 + l15;
                float v = acc[m][n][j];
                if (EPI == 0) {
                    if (gc < N) Cf[(size_t)gr * ldc + gc] = v;
                } else if (EPI == 1) {
                    if (gc < N) Cf[(size_t)gr * ldc + gc] = softplus_f(v + bias[gc]);
                } else if (EPI == 2) {
                    if (gc < N) Cb[(size_t)gr * ldc + gc] = f2bf(v);
                } else { // 3: cols<2048 -> dt_bf (bf16, ld 2048); 2048..2079 -> BC f32 (ld 32)
                    if (gc < D_INNER) Cb[(size_t)gr * D_INNER + gc] = f2bf(v);
                    else if (gc < N_BC) Caux[(size_t)gr * 32 + (gc - D_INNER)] = v;
                }
            }
        }
    }
}

// ---------------- depthwise causal conv (K=4) + SiLU, bf16 in/out ----------
__global__ __launch_bounds__(256) void conv_silu_k(
    const u16* __restrict__ xz,     // [4096][4096] bf16, xi = cols 0..2047
    const float* __restrict__ cw,   // [2048][4] f32
    const float* __restrict__ cb,   // [2048]
    u16* __restrict__ xc)           // [4096][2048] bf16
{
    int idx = blockIdx.x * 256 + threadIdx.x;
    if (idx >= M_ROWS * D_INNER) return;
    int d = idx & (D_INNER - 1);
    int m = idx >> 11;
    int l = m & (L_SEQ - 1);
    float4 w = *(const float4*)(cw + d * 4);
    const u16* base = xz + (size_t)m * (2 * D_INNER) + d;
    float acc = cb[d];
    acc = fmaf(bf2f(base[0]), w.w, acc);
    if (l >= 1) acc = fmaf(bf2f(base[-(2 * D_INNER)]), w.z, acc);
    if (l >= 2) acc = fmaf(bf2f(base[-2 * (2 * D_INNER)]), w.y, acc);
    if (l >= 3) acc = fmaf(bf2f(base[-3 * (2 * D_INNER)]), w.x, acc);
    xc[idx] = f2bf(silu_f(acc));
}

// ==================== chunked selective scan ====================
// pass1: per (b, chunk, d): local scan of 32 steps with h0=0, all 16 states
// in registers; record h_loc[16] and sum(delta). No cross-lane ops.
__global__ __launch_bounds__(256) void scan_pass1(
    const float* __restrict__ delta,   // [4096][2048] f32
    const u16* __restrict__ xc,        // [4096][2048] bf16
    const float* __restrict__ BC,      // [4096][32] f32: B=0..15, C=16..31
    const float* __restrict__ A_log,   // [2048][16]
    float* __restrict__ hbuf,          // [B][NCH][16][2048]
    float* __restrict__ sumd)          // [B][NCH][2048]
{
    __shared__ float Bs[CHUNK][16];
    const int bid = blockIdx.x;
    const int c = bid & (NCH - 1);
    const int dblk = (bid >> 5) & 7;
    const int b = bid >> 8;
    const int tid = threadIdx.x;
    const int d = dblk * 256 + tid;
    const int row0 = b * L_SEQ + c * CHUNK;

    if (tid < CHUNK * 16) {
        int l = tid >> 4, n = tid & 15;
        Bs[l][n] = BC[(size_t)(row0 + l) * 32 + n];
    }
    __syncthreads();

    float Ac[16], h[16];
#pragma unroll
    for (int n = 0; n < 16; ++n) { Ac[n] = -__expf(A_log[d * 16 + n]); h[n] = 0.f; }
    float sd = 0.f;

    for (int l = 0; l < CHUNK; ++l) {
        size_t r = (size_t)(row0 + l);
        float dv = delta[r * D_INNER + d];
        float xv = bf2f(xc[r * D_INNER + d]);
        float t = dv * xv;
        sd += dv;
#pragma unroll
        for (int n = 0; n < 16; ++n) {
            float dA = __expf(dv * Ac[n]);
            h[n] = fmaf(dA, h[n], t * Bs[l][n]);
        }
    }
    size_t base = ((size_t)(b * NCH + c) * 16) * D_INNER + d;
#pragma unroll
    for (int n = 0; n < 16; ++n) hbuf[base + (size_t)n * D_INNER] = h[n];
    sumd[(size_t)(b * NCH + c) * D_INNER + d] = sd;
}

// pass2: per (b,d,n): carry across the 32 chunks. prod(exp(dv*Ac)) over a
// chunk == exp(Ac * sum(dv)). In-place: hbuf[c] := carry-in for chunk c.
__global__ __launch_bounds__(256) void scan_pass2(
    const float* __restrict__ A_log,
    const float* __restrict__ sumd,
    float* __restrict__ hbuf)
{
    const int bid = blockIdx.x;          // grid = B*16*8 = 512
    const int dblk = bid & 7;
    const int n = (bid >> 3) & 15;
    const int b = bid >> 7;
    const int d = dblk * 256 + threadIdx.x;
    const float Ac = -__expf(A_log[d * 16 + n]);
    float carry = 0.f;
    for (int c = 0; c < NCH; ++c) {
        float sd = sumd[(size_t)(b * NCH + c) * D_INNER + d];
        size_t idx = ((size_t)(b * NCH + c) * 16 + n) * D_INNER + d;
        float tmp = hbuf[idx];
        hbuf[idx] = carry;
        carry = fmaf(__expf(Ac * sd), carry, tmp);
    }
}

// pass3: per (b, chunk, d): rerun local scan from true carry-in; emit
// y = C.h + x*D, gated with silu(z).
__global__ __launch_bounds__(256) void scan_pass3(
    const float* __restrict__ delta,
    const u16* __restrict__ xc,
    const float* __restrict__ BC,
    const u16* __restrict__ xz,        // z at col 2048+d, ld 4096
    const float* __restrict__ A_log,
    const float* __restrict__ Dp,
    const float* __restrict__ hbuf,    // carry-in per chunk
    u16* __restrict__ yg)              // [4096][2048] bf16
{
    __shared__ float BCs[CHUNK][32];
    const int bid = blockIdx.x;
    const int c = bid & (NCH - 1);
    const int dblk = (bid >> 5) & 7;
    const int b = bid >> 8;
    const int tid = threadIdx.x;
    const int d = dblk * 256 + tid;
    const int row0 = b * L_SEQ + c * CHUNK;

#pragma unroll
    for (int i = 0; i < (CHUNK * 32) / 256; ++i) {
        int e = tid + i * 256;
        int l = e >> 5, j = e & 31;
        BCs[l][j] = BC[(size_t)(row0 + l) * 32 + j];
    }
    __syncthreads();

    float Ac[16], h[16];
    size_t base = ((size_t)(b * NCH + c) * 16) * D_INNER + d;
#pragma unroll
    for (int n = 0; n < 16; ++n) {
        Ac[n] = -__expf(A_log[d * 16 + n]);
        h[n] = hbuf[base + (size_t)n * D_INNER];
    }
    const float Dv = Dp[d];

    for (int l = 0; l < CHUNK; ++l) {
        size_t r = (size_t)(row0 + l);
        float dv = delta[r * D_INNER + d];
        float xv = bf2f(xc[r * D_INNER + d]);
        float t = dv * xv;
        float y = xv * Dv;
#pragma unroll
        for (int n = 0; n < 16; ++n) {
            float dA = __expf(dv * Ac[n]);
            h[n] = fmaf(dA, h[n], t * BCs[l][n]);
            y = fmaf(BCs[l][16 + n], h[n], y);
        }
        float zv = bf2f(xz[r * (2 * D_INNER) + D_INNER + d]);
        yg[r * D_INNER + d] = f2bf(y * silu_f(zv));
    }
}

// ---------------- host launch ----------------
extern "C" void kernel_launch(void* const* d_in, const int* in_sizes, int n_in,
                              void* d_out, int out_size, void* d_ws, size_t ws_size,
                              hipStream_t stream)
{
    const float* x          = (const float*)d_in[0];
    const float* in_proj_w  = (const float*)d_in[1];
    const float* conv_w     = (const float*)d_in[2];
    const float* conv_b     = (const float*)d_in[3];
    const float* x_proj_w   = (const float*)d_in[4];
    const float* dt_proj_w  = (const float*)d_in[5];
    const float* dt_proj_b  = (const float*)d_in[6];
    const float* A_log      = (const float*)d_in[7];
    const float* D_param    = (const float*)d_in[8];
    const float* out_proj_w = (const float*)d_in[9];
    float* out = (float*)d_out;

    char* p = (char*)d_ws;
    u16* x_bf  = (u16*)p;  p += (size_t)M_ROWS * D_MODEL * 2;          // 8 MB
    u16* w1_bf = (u16*)p;  p += (size_t)2 * D_INNER * D_MODEL * 2;     // 8 MB
    u16* w3_bf = (u16*)p;  p += (size_t)N_BC * D_INNER * 2;            // 8.5 MB
    u16* w4_bf = (u16*)p;  p += (size_t)D_INNER * D_INNER * 2;         // 8 MB
    u16* w6_bf = (u16*)p;  p += (size_t)D_MODEL * D_INNER * 2;         // 4 MB
    u16* xz_bf = (u16*)p;  p += (size_t)M_ROWS * 2 * D_INNER * 2;      // 32 MB
    u16* xc_bf = (u16*)p;  p += (size_t)M_ROWS * D_INNER * 2;          // 16 MB
    u16* dt_bf = (u16*)p;  p += (size_t)M_ROWS * D_INNER * 2;          // 16 MB
    float* BC  = (float*)p; p += (size_t)M_ROWS * 32 * 4;              // 0.5 MB
    float* delta = (float*)p; p += (size_t)M_ROWS * D_INNER * 4;       // 32 MB
    u16* yg_bf = (u16*)p;                                              // 16 MB
    // aliases over dead buffers (dt_bf dead after GEMM4, x_bf dead after GEMM1):
    float* hbuf = (float*)dt_bf;   // B*NCH*16*2048 f32 = 16 MB
    float* sumd = (float*)x_bf;    // B*NCH*2048 f32 = 1 MB

    dim3 blk(256);
    auto cvt = [&](const float* src, u16* dst, size_t n) {
        int n4 = (int)(n / 4);
        cvt_bf16_k<<<dim3((n4 + 255) / 256), blk, 0, stream>>>(src, dst, n4);
    };
    cvt(x,          x_bf,  (size_t)M_ROWS * D_MODEL);
    cvt(in_proj_w,  w1_bf, (size_t)2 * D_INNER * D_MODEL);
    cvt(x_proj_w,   w3_bf, (size_t)N_BC * D_INNER);
    cvt(dt_proj_w,  w4_bf, (size_t)D_INNER * D_INNER);
    cvt(out_proj_w, w6_bf, (size_t)D_MODEL * D_INNER);

    // 1) xz = x @ in_proj^T -> bf16   [4096,4096] K=1024
    gemm_bf16<2><<<dim3(32, 32), blk, 0, stream>>>(
        x_bf, D_MODEL, w1_bf, D_MODEL, M_ROWS, 2 * D_INNER, D_MODEL, 2 * D_INNER,
        nullptr, nullptr, xz_bf, nullptr);

    // 2) conv + silu -> xc_bf
    conv_silu_k<<<dim3((M_ROWS * D_INNER) / 256), blk, 0, stream>>>(
        xz_bf, conv_w, conv_b, xc_bf);

    // 3) deltaBC = xc @ x_proj^T -> dt_bf (cols<2048) + BC f32   [4096,2080] K=2048
    gemm_bf16<3><<<dim3(17, 32), blk, 0, stream>>>(
        xc_bf, D_INNER, w3_bf, D_INNER, M_ROWS, N_BC, D_INNER, 0,
        nullptr, nullptr, dt_bf, BC);

    // 4) delta = softplus(dt @ dt_proj^T + b) -> f32   [4096,2048] K=2048
    gemm_bf16<1><<<dim3(16, 32), blk, 0, stream>>>(
        dt_bf, D_INNER, w4_bf, D_INNER, M_ROWS, D_INNER, D_INNER, D_INNER,
        dt_proj_b, delta, nullptr, nullptr);

    // 5) chunked scan: pass1 local scans -> pass2 chunk carries -> pass3 emit
    scan_pass1<<<dim3(B_SZ * 8 * NCH), blk, 0, stream>>>(
        delta, xc_bf, BC, A_log, hbuf, sumd);
    scan_pass2<<<dim3(B_SZ * 16 * 8), blk, 0, stream>>>(
        A_log, sumd, hbuf);
    scan_pass3<<<dim3(B_SZ * 8 * NCH), blk, 0, stream>>>(
        delta, xc_bf, BC, xz_bf, A_log, D_param, hbuf, yg_bf);

    // 6) out = yg @ out_proj^T -> f32   [4096,1024] K=2048
    gemm_bf16<0><<<dim3(8, 32), blk, 0, stream>>>(
        yg_bf, D_INNER, w6_bf, D_INNER, M_ROWS, D_MODEL, D_INNER, D_MODEL,
        nullptr, out, nullptr, nullptr);
}

// Round 5
// 342.491 us; speedup vs baseline: 2.7297x; 1.0573x over previous
//
#include <hip/hip_runtime.h>
#include <math.h>

// ---------------- Problem constants ----------------
#define B_SZ 4
#define L_SEQ 1024
#define D_MODEL 1024
#define D_INNER 2048
#define D_STATE 16
#define N_BC 2080
#define M_ROWS (B_SZ * L_SEQ)   // 4096
#define CHUNK 32
#define NCH (L_SEQ / CHUNK)     // 32

typedef unsigned short u16;
typedef __bf16 bf16x8 __attribute__((ext_vector_type(8)));
typedef float f32x4 __attribute__((ext_vector_type(4)));

typedef const __attribute__((address_space(1))) unsigned short glb_u16;
typedef __attribute__((address_space(3))) unsigned short lds_u16;

__device__ __forceinline__ void gload_lds16(const u16* g, u16* l) {
    // direct global->LDS DMA, 16B per lane; LDS dest = wave-uniform base + lane*16
    __builtin_amdgcn_global_load_lds((glb_u16*)g, (lds_u16*)l, 16, 0, 0);
}

__device__ __forceinline__ float bf2f(u16 u) {
    union { unsigned int i; float f; } v; v.i = ((unsigned int)u) << 16; return v.f;
}
__device__ __forceinline__ u16 f2bf(float f) {
    union { float f; unsigned int i; } v; v.f = f;
    return (u16)((v.i + 0x7FFFu + ((v.i >> 16) & 1u)) >> 16);   // RNE
}
__device__ __forceinline__ float softplus_f(float v) {
    return fmaxf(v, 0.f) + log1pf(expf(-fabsf(v)));
}
__device__ __forceinline__ float silu_f(float v) {
    return v / (1.f + expf(-v));
}

// ---------------- f32 -> bf16 convert ----------------
__global__ __launch_bounds__(256) void cvt_bf16_k(const float* __restrict__ in,
                                                  u16* __restrict__ out, int n4) {
    int i = blockIdx.x * 256 + threadIdx.x;
    if (i >= n4) return;
    float4 v = *(const float4*)(in + (size_t)i * 4);
    ushort4 o;
    o.x = f2bf(v.x); o.y = f2bf(v.y); o.z = f2bf(v.z); o.w = f2bf(v.w);
    *(ushort4*)(out + (size_t)i * 4) = o;
}

// ---------------- bf16 MFMA GEMM: C[M,N] = A[M,K] * W[N,K]^T ----------------
// 128x128 tile, BK=32, 4 waves, each wave 64x64 (4x4 fragments 16x16x32).
// Staging: global_load_lds w16, linear LDS [128][32]bf16, source pre-swizzled
// with involution quad ^= (row>>1)&3; ds_read applies the same XOR -> <=2-way.
// EPI: 0 f32 store; 1 softplus(v+bias[n]) f32; 2 bf16 store; 3 split dt/BC
template <int EPI>
__global__ __launch_bounds__(256, 2) void gemm_bf16(
    const u16* __restrict__ A, int lda,
    const u16* __restrict__ W, int ldw,
    int M, int N, int K, int ldc,
    const float* __restrict__ bias,
    float* __restrict__ Cf, u16* __restrict__ Cb, float* __restrict__ Caux)
{
    __shared__ __align__(16) u16 As[128 * 32];   // 8 KB
    __shared__ __align__(16) u16 Ws[128 * 32];   // 8 KB

    const int tid = threadIdx.x;
    const int lane = tid & 63;
    const int wave = tid >> 6;
    const int wr = wave >> 1;           // 0..1 row-half of 64
    const int wc = wave & 1;            // 0..1 col-half of 64
    const int bm = blockIdx.y * 128;
    const int bn = blockIdx.x * 128;
    const int l15 = lane & 15;
    const int lq = lane >> 4;           // k-quarter 0..3

    // staging lane geometry: chunk = 16 rows x 32 cols = 1024B; lane covers
    // row lane>>2, swizzled quad ((lane&3) ^ ((lane>>3)&3))
    const int lrow = lane >> 2;
    const int qoff = (((lane & 3) ^ ((lane >> 3) & 3))) * 8;   // bf16 elements
    // fragment read: row r -> quad (lq ^ ((r>>1)&3)); (r>>1)&3 == (l15>>1)&3
    const int rq = ((lq ^ ((l15 >> 1) & 3))) * 8;

    f32x4 acc[4][4];
#pragma unroll
    for (int m = 0; m < 4; ++m)
#pragma unroll
        for (int n = 0; n < 4; ++n) acc[m][n] = f32x4{0.f, 0.f, 0.f, 0.f};

    for (int k0 = 0; k0 < K; k0 += 32) {
#pragma unroll
        for (int i = 0; i < 2; ++i) {
            const int c = wave * 2 + i;          // chunk 0..7
            const int row = c * 16 + lrow;       // tile row 0..127
            gload_lds16(A + (size_t)(bm + row) * lda + k0 + qoff, &As[c * 512]);
            int wrow = bn + row; if (wrow >= N) wrow = N - 1;
            gload_lds16(W + (size_t)wrow * ldw + k0 + qoff, &Ws[c * 512]);
        }
        __syncthreads();

        bf16x8 af[4], bfr[4];
#pragma unroll
        for (int m = 0; m < 4; ++m) {
            int r = wr * 64 + m * 16 + l15;
            af[m] = *reinterpret_cast<const bf16x8*>(&As[r * 32 + rq]);
        }
#pragma unroll
        for (int n = 0; n < 4; ++n) {
            int r = wc * 64 + n * 16 + l15;
            bfr[n] = *reinterpret_cast<const bf16x8*>(&Ws[r * 32 + rq]);
        }
#pragma unroll
        for (int m = 0; m < 4; ++m)
#pragma unroll
            for (int n = 0; n < 4; ++n)
                acc[m][n] = __builtin_amdgcn_mfma_f32_16x16x32_bf16(af[m], bfr[n], acc[m][n], 0, 0, 0);
        __syncthreads();
    }

    // epilogue: D layout col=lane&15, row=(lane>>4)*4+reg  [m89-verified]
#pragma unroll
    for (int m = 0; m < 4; ++m) {
#pragma unroll
        for (int n = 0; n < 4; ++n) {
#pragma unroll
            for (int j = 0; j < 4; ++j) {
                int gr = bm + wr * 64 + m * 16 + lq * 4 + j;
                int gc = bn + wc * 64 + n * 16 + l15;
                float v = acc[m][n][j];
                if (EPI == 0) {
                    if (gc < N) Cf[(size_t)gr * ldc + gc] = v;
                } else if (EPI == 1) {
                    if (gc < N) Cf[(size_t)gr * ldc + gc] = softplus_f(v + bias[gc]);
                } else if (EPI == 2) {
                    if (gc < N) Cb[(size_t)gr * ldc + gc] = f2bf(v);
                } else { // 3: cols<2048 -> dt_bf (bf16, ld 2048); 2048..2079 -> BC f32 (ld 32)
                    if (gc < D_INNER) Cb[(size_t)gr * D_INNER + gc] = f2bf(v);
                    else if (gc < N_BC) Caux[(size_t)gr * 32 + (gc - D_INNER)] = v;
                }
            }
        }
    }
}

// ---------------- depthwise causal conv (K=4) + SiLU, bf16 in/out ----------
__global__ __launch_bounds__(256) void conv_silu_k(
    const u16* __restrict__ xz,     // [4096][4096] bf16, xi = cols 0..2047
    const float* __restrict__ cw,   // [2048][4] f32
    const float* __restrict__ cb,   // [2048]
    u16* __restrict__ xc)           // [4096][2048] bf16
{
    int idx = blockIdx.x * 256 + threadIdx.x;
    if (idx >= M_ROWS * D_INNER) return;
    int d = idx & (D_INNER - 1);
    int m = idx >> 11;
    int l = m & (L_SEQ - 1);
    float4 w = *(const float4*)(cw + d * 4);
    const u16* base = xz + (size_t)m * (2 * D_INNER) + d;
    float acc = cb[d];
    acc = fmaf(bf2f(base[0]), w.w, acc);
    if (l >= 1) acc = fmaf(bf2f(base[-(2 * D_INNER)]), w.z, acc);
    if (l >= 2) acc = fmaf(bf2f(base[-2 * (2 * D_INNER)]), w.y, acc);
    if (l >= 3) acc = fmaf(bf2f(base[-3 * (2 * D_INNER)]), w.x, acc);
    xc[idx] = f2bf(silu_f(acc));
}

// ==================== chunked selective scan ====================
// pass1: per (b, chunk, d): local scan of 32 steps with h0=0, all 16 states
// in registers; record h_loc[16] and sum(delta). No cross-lane ops.
__global__ __launch_bounds__(256) void scan_pass1(
    const float* __restrict__ delta,   // [4096][2048] f32
    const u16* __restrict__ xc,        // [4096][2048] bf16
    const float* __restrict__ BC,      // [4096][32] f32: B=0..15, C=16..31
    const float* __restrict__ A_log,   // [2048][16]
    float* __restrict__ hbuf,          // [B][NCH][16][2048]
    float* __restrict__ sumd)          // [B][NCH][2048]
{
    __shared__ float Bs[CHUNK][16];
    const int bid = blockIdx.x;
    const int c = bid & (NCH - 1);
    const int dblk = (bid >> 5) & 7;
    const int b = bid >> 8;
    const int tid = threadIdx.x;
    const int d = dblk * 256 + tid;
    const int row0 = b * L_SEQ + c * CHUNK;

    if (tid < CHUNK * 16) {
        int l = tid >> 4, n = tid & 15;
        Bs[l][n] = BC[(size_t)(row0 + l) * 32 + n];
    }
    __syncthreads();

    float Ac[16], h[16];
#pragma unroll
    for (int n = 0; n < 16; ++n) { Ac[n] = -__expf(A_log[d * 16 + n]); h[n] = 0.f; }
    float sd = 0.f;

    for (int l = 0; l < CHUNK; ++l) {
        size_t r = (size_t)(row0 + l);
        float dv = delta[r * D_INNER + d];
        float xv = bf2f(xc[r * D_INNER + d]);
        float t = dv * xv;
        sd += dv;
#pragma unroll
        for (int n = 0; n < 16; ++n) {
            float dA = __expf(dv * Ac[n]);
            h[n] = fmaf(dA, h[n], t * Bs[l][n]);
        }
    }
    size_t base = ((size_t)(b * NCH + c) * 16) * D_INNER + d;
#pragma unroll
    for (int n = 0; n < 16; ++n) hbuf[base + (size_t)n * D_INNER] = h[n];
    sumd[(size_t)(b * NCH + c) * D_INNER + d] = sd;
}

// pass2: per (b,d,n): carry across the 32 chunks. prod(exp(dv*Ac)) over a
// chunk == exp(Ac * sum(dv)). In-place: hbuf[c] := carry-in for chunk c.
__global__ __launch_bounds__(256) void scan_pass2(
    const float* __restrict__ A_log,
    const float* __restrict__ sumd,
    float* __restrict__ hbuf)
{
    const int bid = blockIdx.x;          // grid = B*16*8 = 512
    const int dblk = bid & 7;
    const int n = (bid >> 3) & 15;
    const int b = bid >> 7;
    const int d = dblk * 256 + threadIdx.x;
    const float Ac = -__expf(A_log[d * 16 + n]);
    float carry = 0.f;
    for (int c = 0; c < NCH; ++c) {
        float sd = sumd[(size_t)(b * NCH + c) * D_INNER + d];
        size_t idx = ((size_t)(b * NCH + c) * 16 + n) * D_INNER + d;
        float tmp = hbuf[idx];
        hbuf[idx] = carry;
        carry = fmaf(__expf(Ac * sd), carry, tmp);
    }
}

// pass3: per (b, chunk, d): rerun local scan from true carry-in; emit
// y = C.h + x*D, gated with silu(z).
__global__ __launch_bounds__(256) void scan_pass3(
    const float* __restrict__ delta,
    const u16* __restrict__ xc,
    const float* __restrict__ BC,
    const u16* __restrict__ xz,        // z at col 2048+d, ld 4096
    const float* __restrict__ A_log,
    const float* __restrict__ Dp,
    const float* __restrict__ hbuf,    // carry-in per chunk
    u16* __restrict__ yg)              // [4096][2048] bf16
{
    __shared__ float BCs[CHUNK][32];
    const int bid = blockIdx.x;
    const int c = bid & (NCH - 1);
    const int dblk = (bid >> 5) & 7;
    const int b = bid >> 8;
    const int tid = threadIdx.x;
    const int d = dblk * 256 + tid;
    const int row0 = b * L_SEQ + c * CHUNK;

#pragma unroll
    for (int i = 0; i < (CHUNK * 32) / 256; ++i) {
        int e = tid + i * 256;
        int l = e >> 5, j = e & 31;
        BCs[l][j] = BC[(size_t)(row0 + l) * 32 + j];
    }
    __syncthreads();

    float Ac[16], h[16];
    size_t base = ((size_t)(b * NCH + c) * 16) * D_INNER + d;
#pragma unroll
    for (int n = 0; n < 16; ++n) {
        Ac[n] = -__expf(A_log[d * 16 + n]);
        h[n] = hbuf[base + (size_t)n * D_INNER];
    }
    const float Dv = Dp[d];

    for (int l = 0; l < CHUNK; ++l) {
        size_t r = (size_t)(row0 + l);
        float dv = delta[r * D_INNER + d];
        float xv = bf2f(xc[r * D_INNER + d]);
        float t = dv * xv;
        float y = xv * Dv;
#pragma unroll
        for (int n = 0; n < 16; ++n) {
            float dA = __expf(dv * Ac[n]);
            h[n] = fmaf(dA, h[n], t * BCs[l][n]);
            y = fmaf(BCs[l][16 + n], h[n], y);
        }
        float zv = bf2f(xz[r * (2 * D_INNER) + D_INNER + d]);
        yg[r * D_INNER + d] = f2bf(y * silu_f(zv));
    }
}

// ---------------- host launch ----------------
extern "C" void kernel_launch(void* const* d_in, const int* in_sizes, int n_in,
                              void* d_out, int out_size, void* d_ws, size_t ws_size,
                              hipStream_t stream)
{
    const float* x          = (const float*)d_in[0];
    const float* in_proj_w  = (const float*)d_in[1];
    const float* conv_w     = (const float*)d_in[2];
    const float* conv_b     = (const float*)d_in[3];
    const float* x_proj_w   = (const float*)d_in[4];
    const float* dt_proj_w  = (const float*)d_in[5];
    const float* dt_proj_b  = (const float*)d_in[6];
    const float* A_log      = (const float*)d_in[7];
    const float* D_param    = (const float*)d_in[8];
    const float* out_proj_w = (const float*)d_in[9];
    float* out = (float*)d_out;

    char* p = (char*)d_ws;
    u16* x_bf  = (u16*)p;  p += (size_t)M_ROWS * D_MODEL * 2;          // 8 MB
    u16* w1_bf = (u16*)p;  p += (size_t)2 * D_INNER * D_MODEL * 2;     // 8 MB
    u16* w3_bf = (u16*)p;  p += (size_t)N_BC * D_INNER * 2;            // 8.5 MB
    u16* w4_bf = (u16*)p;  p += (size_t)D_INNER * D_INNER * 2;         // 8 MB
    u16* w6_bf = (u16*)p;  p += (size_t)D_MODEL * D_INNER * 2;         // 4 MB
    u16* xz_bf = (u16*)p;  p += (size_t)M_ROWS * 2 * D_INNER * 2;      // 32 MB
    u16* xc_bf = (u16*)p;  p += (size_t)M_ROWS * D_INNER * 2;          // 16 MB
    u16* dt_bf = (u16*)p;  p += (size_t)M_ROWS * D_INNER * 2;          // 16 MB
    float* BC  = (float*)p; p += (size_t)M_ROWS * 32 * 4;              // 0.5 MB
    float* delta = (float*)p; p += (size_t)M_ROWS * D_INNER * 4;       // 32 MB
    u16* yg_bf = (u16*)p;                                              // 16 MB
    // aliases over dead buffers (dt_bf dead after GEMM4, x_bf dead after GEMM1):
    float* hbuf = (float*)dt_bf;   // B*NCH*16*2048 f32 = 16 MB
    float* sumd = (float*)x_bf;    // B*NCH*2048 f32 = 1 MB

    dim3 blk(256);
    auto cvt = [&](const float* src, u16* dst, size_t n) {
        int n4 = (int)(n / 4);
        cvt_bf16_k<<<dim3((n4 + 255) / 256), blk, 0, stream>>>(src, dst, n4);
    };
    cvt(x,          x_bf,  (size_t)M_ROWS * D_MODEL);
    cvt(in_proj_w,  w1_bf, (size_t)2 * D_INNER * D_MODEL);
    cvt(x_proj_w,   w3_bf, (size_t)N_BC * D_INNER);
    cvt(dt_proj_w,  w4_bf, (size_t)D_INNER * D_INNER);
    cvt(out_proj_w, w6_bf, (size_t)D_MODEL * D_INNER);

    // 1) xz = x @ in_proj^T -> bf16   [4096,4096] K=1024
    gemm_bf16<2><<<dim3(32, 32), blk, 0, stream>>>(
        x_bf, D_MODEL, w1_bf, D_MODEL, M_ROWS, 2 * D_INNER, D_MODEL, 2 * D_INNER,
        nullptr, nullptr, xz_bf, nullptr);

    // 2) conv + silu -> xc_bf
    conv_silu_k<<<dim3((M_ROWS * D_INNER) / 256), blk, 0, stream>>>(
        xz_bf, conv_w, conv_b, xc_bf);

    // 3) deltaBC = xc @ x_proj^T -> dt_bf (cols<2048) + BC f32   [4096,2080] K=2048
    gemm_bf16<3><<<dim3(17, 32), blk, 0, stream>>>(
        xc_bf, D_INNER, w3_bf, D_INNER, M_ROWS, N_BC, D_INNER, 0,
        nullptr, nullptr, dt_bf, BC);

    // 4) delta = softplus(dt @ dt_proj^T + b) -> f32   [4096,2048] K=2048
    gemm_bf16<1><<<dim3(16, 32), blk, 0, stream>>>(
        dt_bf, D_INNER, w4_bf, D_INNER, M_ROWS, D_INNER, D_INNER, D_INNER,
        dt_proj_b, delta, nullptr, nullptr);

    // 5) chunked scan: pass1 local scans -> pass2 chunk carries -> pass3 emit
    scan_pass1<<<dim3(B_SZ * 8 * NCH), blk, 0, stream>>>(
        delta, xc_bf, BC, A_log, hbuf, sumd);
    scan_pass2<<<dim3(B_SZ * 16 * 8), blk, 0, stream>>>(
        A_log, sumd, hbuf);
    scan_pass3<<<dim3(B_SZ * 8 * NCH), blk, 0, stream>>>(
        delta, xc_bf, BC, xz_bf, A_log, D_param, hbuf, yg_bf);

    // 6) out = yg @ out_proj^T -> f32   [4096,1024] K=2048
    gemm_bf16<0><<<dim3(8, 32), blk, 0, stream>>>(
        yg_bf, D_INNER, w6_bf, D_INNER, M_ROWS, D_MODEL, D_INNER, D_MODEL,
        nullptr, out, nullptr, nullptr);
}